// Round 8
// baseline (76.185 us; speedup 1.0000x reference)
//
#include <hip/hip_runtime.h>

#define THREADS 1024
#define DIN 60
#define HN 256
#define DOUT 360

typedef __attribute__((ext_vector_type(8))) short short8;
typedef __attribute__((ext_vector_type(4))) float f32x4;
typedef __attribute__((ext_vector_type(2))) float f32x2;
typedef __attribute__((ext_vector_type(4))) unsigned int u32x4;

// d_ws layout (bytes); total 231424 B
#define WS_CBF   0            // 2048 * 16 B = 32768  (centres bf16, [row][pc 0..7], pc=c^(row&7))
#define WS_CN    32768        // 256 * {ns2, ns2*c2} = 2048 B   (ns2 = -sigma^2*log2e)
#define WS_W2    34816        // 384 rows * 32 chunks * 16 B = 196608 (bf16, permuted+swizzled)

__device__ __forceinline__ short bf16_bits(float f) {   // prep-side only
    union { float f; unsigned u; } v; v.f = f;
    unsigned r = (v.u + 0x7FFFu + ((v.u >> 16) & 1u)) >> 16;
    return (short)(unsigned short)r;
}

__device__ __forceinline__ unsigned pk_bf16(float a, float b) {
    unsigned r;
    asm("v_cvt_pk_bf16_f32 %0, %1, %2" : "=v"(r) : "v"(a), "v"(b));
    return r;   // low16 = bf16(a), high16 = bf16(b)
}

__device__ __forceinline__ void gload16(const void* g, void* lds) {
    __builtin_amdgcn_global_load_lds(
        (const __attribute__((address_space(1))) unsigned int*)(uintptr_t)g,
        (__attribute__((address_space(3))) unsigned int*)(unsigned int)(uintptr_t)lds,
        16, 0, 0);
}

// ---------------- prep: convert/permute/swizzle constants into ws ----------------
__global__ void prep(const float* __restrict__ centres, const float* __restrict__ sigmas,
                     const float* __restrict__ W2, short* __restrict__ ws)
{
    int t = blockIdx.x * 256 + threadIdx.x;
    if (t < 12288) {
        // W2: [row 0..383][pc 0..31] short8; pc = c ^ (row&7); k = c*8..c*8+7
        int row = t >> 5, pc = t & 31;
        int c = pc ^ (row & 7);
        short8 v = {0,0,0,0,0,0,0,0};
        if (row < DOUT) {
            int rr = row / 12, jj = row % 12;
            int f = rr / 3, kk = rr % 3;
            int o = f * 36 + jj * 3 + kk;              // fold output col permutation
            const float* src = W2 + o * HN + c * 8;
            #pragma unroll
            for (int i = 0; i < 8; ++i) v[i] = bf16_bits(src[i]);
        }
        *(short8*)(ws + (WS_W2 / 2) + t * 8) = v;
    } else if (t < 14336) {
        // centres bf16: [row 0..255][pc 0..7], pc = c ^ (row&7), k padded 60->64
        int j = t - 12288;
        int row = j >> 3, p = j & 7;
        int c = p ^ (row & 7);
        short8 v = {0,0,0,0,0,0,0,0};
        #pragma unroll
        for (int i = 0; i < 8; ++i) {
            int k = c * 8 + i;
            if (k < DIN) v[i] = bf16_bits(centres[row * DIN + k]);
        }
        *(short8*)(ws + (WS_CBF / 2) + j * 8) = v;
    } else if (t < 14592) {
        int i = t - 14336;
        const float* cr = centres + i * DIN;
        float s = 0.f;
        #pragma unroll
        for (int d = 0; d < DIN; ++d) s = fmaf(cr[d], cr[d], s);
        float sg = sigmas[i];
        float ns2 = -sg * sg * 1.44269504088896340736f;
        f32x2 v; v[0] = ns2; v[1] = ns2 * s;           // {ns2, ns2*c2}
        *(f32x2*)(ws + (WS_CN / 2) + i * 4) = v;
    }
}

// --- main: persistent 1024-thr block (1/CU, 4 waves/SIMD), all operands LDS-resident ---
__global__ __launch_bounds__(THREADS, 4)
void rbf_main(const float* __restrict__ x, const short* __restrict__ ws,
              float* __restrict__ out)
{
    __shared__ short8 w2h[6144];     // 96 KB: 192 rows x 32 chunks (this half's cols)
    __shared__ short8 cbf[2048];     // 32 KB: 256 rows x 8 chunks
    __shared__ f32x2  cnsl[HN];      // 2 KB {ns2, ns2*c2}

    const int tid   = threadIdx.x;
    const int w     = tid >> 6;              // wave 0..15
    const int l15   = tid & 15;
    const int g     = (tid & 63) >> 4;
    const int f     = blockIdx.x & 1;        // column half: [f*192, f*192+192)
    const int sbase = blockIdx.x >> 1;       // 0..127

    // ---- stage everything once (async DMA), one barrier for the whole kernel ----
    #pragma unroll
    for (int i = 0; i < 6; ++i)
        gload16(ws + (WS_W2 / 2) + ((size_t)f * 6144 + i * THREADS + tid) * 8,
                (char*)w2h + (i * THREADS + tid) * 16);
    #pragma unroll
    for (int i = 0; i < 2; ++i)
        gload16(ws + (WS_CBF / 2) + (i * THREADS + tid) * 8, (char*)cbf + (i * THREADS + tid) * 16);
    if (tid < 128)
        gload16(ws + (WS_CN / 2) + tid * 8, (char*)cnsl + tid * 16);

    // ---- first task's x: lane (l15,g) holds row l15, k = kt*32 + g*8 + (0..7) ----
    // wave task: row-tile rt = sbase*64 + it*16 + w  (it = 0..3), rows [rt*16, rt*16+16)
    int rbase = sbase * 1024 + w * 16;
    f32x4 xa[2][2];
    {
        const float* xr = x + (size_t)(rbase + l15) * DIN;
        #pragma unroll
        for (int kt = 0; kt < 2; ++kt) {
            int k0 = kt * 32 + g * 8;
            xa[kt][0] = *(const f32x4*)(xr + k0);
            xa[kt][1] = (k0 + 4 < DIN) ? *(const f32x4*)(xr + k0 + 4) : (f32x4){0.f,0.f,0.f,0.f};
        }
    }

    __syncthreads();   // LDS resident; no barriers, no LDS writes after this

    for (int it = 0; it < 4; ++it) {
        // ---- x2 (4 g-lanes of a row partition k; reduce across them) ----
        float p2 = 0.f;
        #pragma unroll
        for (int kt = 0; kt < 2; ++kt)
            #pragma unroll
            for (int h = 0; h < 2; ++h)
                #pragma unroll
                for (int i = 0; i < 4; ++i) p2 = fmaf(xa[kt][h][i], xa[kt][h][i], p2);
        p2 += __shfl_xor(p2, 16);
        p2 += __shfl_xor(p2, 32);
        const float x2v = p2;

        // ---- x B-fragments (bf16 via cvt_pk) ----
        short8 xb[2];
        #pragma unroll
        for (int kt = 0; kt < 2; ++kt) {
            union { u32x4 u; short8 s; } a;
            a.u[0] = pk_bf16(xa[kt][0][0], xa[kt][0][1]);
            a.u[1] = pk_bf16(xa[kt][0][2], xa[kt][0][3]);
            a.u[2] = pk_bf16(xa[kt][1][0], xa[kt][1][1]);
            a.u[3] = pk_bf16(xa[kt][1][2], xa[kt][1][3]);
            xb[kt] = a.s;
        }

        // ---- prefetch next task's x (+256 rows); latency hides under GEMM1+phi+GEMM2 ----
        if (it < 3) {
            const float* xr = x + (size_t)(rbase + 256 + l15) * DIN;
            #pragma unroll
            for (int kt = 0; kt < 2; ++kt) {
                int k0 = kt * 32 + g * 8;
                xa[kt][0] = *(const f32x4*)(xr + k0);
                xa[kt][1] = (k0 + 4 < DIN) ? *(const f32x4*)(xr + k0 + 4) : (f32x4){0.f,0.f,0.f,0.f};
            }
        }

        // ---- GEMM1 (swapped: A=centres, B=x). D col=l15=batch row, h=nt*16+g*4+r ----
        f32x4 acc1[16];
        #pragma unroll
        for (int nt = 0; nt < 16; ++nt) acc1[nt] = (f32x4){0.f, 0.f, 0.f, 0.f};
        __builtin_amdgcn_s_setprio(1);
        #pragma unroll
        for (int nt = 0; nt < 16; ++nt) {
            int row = nt * 16 + l15;
            #pragma unroll
            for (int kt = 0; kt < 2; ++kt) {
                short8 cf = cbf[row * 8 + ((kt * 4 + g) ^ (row & 7))];
                acc1[nt] = __builtin_amdgcn_mfma_f32_16x16x32_bf16(cf, xb[kt], acc1[nt], 0, 0, 0);
            }
        }
        __builtin_amdgcn_s_setprio(0);

        // ---- phi = exp2(min(ns2*(x2-2S) + ns2c2, 0)), packed bf16-pair words ----
        unsigned pw[16][2];
        #pragma unroll
        for (int nt = 0; nt < 16; ++nt) {
            float ph[4];
            #pragma unroll
            for (int r = 0; r < 4; ++r) {
                f32x2 cn = cnsl[nt * 16 + g * 4 + r];
                float t  = fmaf(-2.f, acc1[nt][r], x2v);
                float ex = fminf(fmaf(cn[0], t, cn[1]), 0.f);
                ph[r] = exp2f(ex);
            }
            pw[nt][0] = pk_bf16(ph[0], ph[1]);
            pw[nt][1] = pk_bf16(ph[2], ph[3]);
        }

        // ---- GEMM2: A=phi (shuffle transpose), B=W2 half. 12 N-tiles x 8 K-steps ----
        f32x4 acc2[12];
        #pragma unroll
        for (int nt = 0; nt < 12; ++nt) acc2[nt] = (f32x4){0.f, 0.f, 0.f, 0.f};

        const int s0 = l15 + ((g & 1) << 5);
        const bool hi = (g >= 2);

        #pragma unroll
        for (int kt = 0; kt < 8; ++kt) {
            int A0 = __shfl((int)pw[2*kt][0],   s0);
            int A1 = __shfl((int)pw[2*kt][1],   s0);
            int C0 = __shfl((int)pw[2*kt+1][0], s0);
            int C1 = __shfl((int)pw[2*kt+1][1], s0);
            int B0 = __shfl((int)pw[2*kt][0],   s0 + 16);
            int B1 = __shfl((int)pw[2*kt][1],   s0 + 16);
            int D0 = __shfl((int)pw[2*kt+1][0], s0 + 16);
            int D1 = __shfl((int)pw[2*kt+1][1], s0 + 16);
            union { u32x4 u; short8 s; } afu;
            afu.u[0] = (unsigned)(hi ? C0 : A0);
            afu.u[1] = (unsigned)(hi ? C1 : A1);
            afu.u[2] = (unsigned)(hi ? D0 : B0);
            afu.u[3] = (unsigned)(hi ? D1 : B1);

            __builtin_amdgcn_s_setprio(1);
            #pragma unroll
            for (int nt = 0; nt < 12; ++nt) {
                int lrow = nt * 16 + l15;
                short8 bf = w2h[lrow * 32 + ((kt * 4 + g) ^ (lrow & 7))];
                acc2[nt] = __builtin_amdgcn_mfma_f32_16x16x32_bf16(afu.s, bf, acc2[nt], 0, 0, 0);
            }
            __builtin_amdgcn_s_setprio(0);
        }

        // ---- store: col = f*192 + nt*16 + l15, rows g*4+r ----
        {
            const size_t orow = (size_t)rbase + g * 4;
            #pragma unroll
            for (int nt = 0; nt < 12; ++nt) {
                int col = f * 192 + nt * 16 + l15;
                if (col < DOUT) {
                    #pragma unroll
                    for (int r = 0; r < 4; ++r)
                        out[(orow + r) * DOUT + col] = acc2[nt][r];
                }
            }
        }

        rbase += 256;   // next task (+16 row-tiles)
    }
}

extern "C" void kernel_launch(void* const* d_in, const int* in_sizes, int n_in,
                              void* d_out, int out_size, void* d_ws, size_t ws_size,
                              hipStream_t stream) {
    const float* x       = (const float*)d_in[0];
    const float* centres = (const float*)d_in[1];
    const float* sigmas  = (const float*)d_in[2];
    const float* W2      = (const float*)d_in[3];
    float* out = (float*)d_out;
    short* ws  = (short*)d_ws;                  // needs 231424 B
    prep<<<dim3(57), dim3(256), 0, stream>>>(centres, sigmas, W2, ws);
    rbf_main<<<dim3(256), dim3(THREADS), 0, stream>>>(x, ws, out);
}

// Round 9
// 71.985 us; speedup vs baseline: 1.0583x; 1.0583x over previous
//
#include <hip/hip_runtime.h>

#define THREADS 512
#define DIN 60
#define HN 256
#define DOUT 360

typedef __attribute__((ext_vector_type(8))) short short8;
typedef __attribute__((ext_vector_type(16))) float f32x16;
typedef __attribute__((ext_vector_type(4))) float f32x4;
typedef __attribute__((ext_vector_type(2))) float f32x2;
typedef __attribute__((ext_vector_type(4))) unsigned int u32x4;

// d_ws layout (bytes); total 231424 B
#define WS_CBF   0            // 2048 * 16 B = 32768  (centres bf16, [row][pc 0..7], pc=c^(row&7))
#define WS_CN    32768        // 256 * {ns2, ns2*c2} = 2048 B   (ns2 = -sigma^2*log2e)
#define WS_W2    34816        // 384 rows * 32 chunks * 16 B = 196608 (bf16, permuted, pc=c^(row&31))

__device__ __forceinline__ short bf16_bits(float f) {   // prep-side only
    union { float f; unsigned u; } v; v.f = f;
    unsigned r = (v.u + 0x7FFFu + ((v.u >> 16) & 1u)) >> 16;
    return (short)(unsigned short)r;
}

__device__ __forceinline__ unsigned pk_bf16(float a, float b) {
    unsigned r;
    asm("v_cvt_pk_bf16_f32 %0, %1, %2" : "=v"(r) : "v"(a), "v"(b));
    return r;   // low16 = bf16(a), high16 = bf16(b)
}

__device__ __forceinline__ void gload16(const void* g, void* lds) {
    __builtin_amdgcn_global_load_lds(
        (const __attribute__((address_space(1))) unsigned int*)(uintptr_t)g,
        (__attribute__((address_space(3))) unsigned int*)(unsigned int)(uintptr_t)lds,
        16, 0, 0);
}

// ---------------- prep: convert/permute/swizzle constants into ws ----------------
__global__ void prep(const float* __restrict__ centres, const float* __restrict__ sigmas,
                     const float* __restrict__ W2, short* __restrict__ ws)
{
    int t = blockIdx.x * 256 + threadIdx.x;
    if (t < 12288) {
        // W2: [row 0..383][pc 0..31] short8; pc = c ^ (row&31); k = c*8..c*8+7
        int row = t >> 5, pc = t & 31;
        int c = pc ^ (row & 31);
        short8 v = {0,0,0,0,0,0,0,0};
        if (row < DOUT) {
            int rr = row / 12, jj = row % 12;
            int f = rr / 3, kk = rr % 3;
            int o = f * 36 + jj * 3 + kk;              // fold output col permutation
            const float* src = W2 + o * HN + c * 8;
            #pragma unroll
            for (int i = 0; i < 8; ++i) v[i] = bf16_bits(src[i]);
        }
        *(short8*)(ws + (WS_W2 / 2) + t * 8) = v;
    } else if (t < 14336) {
        // centres bf16: [row 0..255][pc 0..7], pc = c ^ (row&7), k padded 60->64
        int j = t - 12288;
        int row = j >> 3, p = j & 7;
        int c = p ^ (row & 7);
        short8 v = {0,0,0,0,0,0,0,0};
        #pragma unroll
        for (int i = 0; i < 8; ++i) {
            int k = c * 8 + i;
            if (k < DIN) v[i] = bf16_bits(centres[row * DIN + k]);
        }
        *(short8*)(ws + (WS_CBF / 2) + j * 8) = v;
    } else if (t < 14592) {
        int i = t - 14336;
        const float* cr = centres + i * DIN;
        float s = 0.f;
        #pragma unroll
        for (int d = 0; d < DIN; ++d) s = fmaf(cr[d], cr[d], s);
        float sg = sigmas[i];
        float ns2 = -sg * sg * 1.44269504088896340736f;
        f32x2 v; v[0] = ns2; v[1] = ns2 * s;           // {ns2, ns2*c2}
        *(f32x2*)(ws + (WS_CN / 2) + i * 4) = v;
    }
}

// --- main: persistent 512-thr block (1/CU), 32x32x16 MFMA, all operands LDS-resident ---
__global__ __launch_bounds__(THREADS, 2)
void rbf_main(const float* __restrict__ x, const short* __restrict__ ws,
              float* __restrict__ out)
{
    __shared__ short8 w2h[6144];     // 96 KB: 192 rows x 32 chunks (this half's cols)
    __shared__ short8 cbf[2048];     // 32 KB: 256 rows x 8 chunks
    __shared__ f32x2  cnsl[HN];      // 2 KB {ns2, ns2*c2}

    const int tid   = threadIdx.x;
    const int w     = tid >> 6;              // wave 0..7
    const int lane  = tid & 63;
    const int l31   = lane & 31;
    const int hi    = lane >> 5;
    const int f     = blockIdx.x & 1;        // column half: [f*192, f*192+192)
    const int sbase = blockIdx.x >> 1;       // 0..127 -> rows [sbase*1024, +1024)

    // ---- stage everything once (async DMA), one barrier for the whole kernel ----
    #pragma unroll
    for (int i = 0; i < 12; ++i)
        gload16(ws + (WS_W2 / 2) + ((size_t)f * 6144 + i * THREADS + tid) * 8,
                (char*)w2h + (i * THREADS + tid) * 16);
    #pragma unroll
    for (int i = 0; i < 4; ++i)
        gload16(ws + (WS_CBF / 2) + (i * THREADS + tid) * 8, (char*)cbf + (i * THREADS + tid) * 16);
    if (tid < 128)
        gload16(ws + (WS_CN / 2) + tid * 8, (char*)cnsl + tid * 16);

    // ---- first task's x: lane (l31,hi) = row l31, k = kt*16 + hi*8 + (0..7) ----
    int rbase = sbase * 1024 + w * 32;
    f32x4 xa[4][2];
    {
        const float* xr = x + (size_t)(rbase + l31) * DIN;
        #pragma unroll
        for (int kt = 0; kt < 4; ++kt) {
            int k0 = kt * 16 + hi * 8;
            xa[kt][0] = *(const f32x4*)(xr + k0);
            xa[kt][1] = (k0 + 4 < DIN) ? *(const f32x4*)(xr + k0 + 4) : (f32x4){0.f,0.f,0.f,0.f};
        }
    }
    // pack current xb + x2 (xa dies before first GEMM2)
    float p2 = 0.f;
    #pragma unroll
    for (int kt = 0; kt < 4; ++kt)
        #pragma unroll
        for (int h = 0; h < 2; ++h)
            #pragma unroll
            for (int i = 0; i < 4; ++i) p2 = fmaf(xa[kt][h][i], xa[kt][h][i], p2);
    float x2v = p2 + __shfl_xor(p2, 32);
    short8 xb[4];
    #pragma unroll
    for (int kt = 0; kt < 4; ++kt) {
        union { u32x4 u; short8 s; } a;
        a.u[0] = pk_bf16(xa[kt][0][0], xa[kt][0][1]);
        a.u[1] = pk_bf16(xa[kt][0][2], xa[kt][0][3]);
        a.u[2] = pk_bf16(xa[kt][1][0], xa[kt][1][1]);
        a.u[3] = pk_bf16(xa[kt][1][2], xa[kt][1][3]);
        xb[kt] = a.s;
    }

    __syncthreads();   // LDS resident; no barriers, no LDS writes after this

    for (int it = 0; it < 4; ++it) {
        // ---- issue next task's x loads early (latency hides under GEMM1+phi) ----
        if (it < 3) {
            const float* xr = x + (size_t)(rbase + 256 + l31) * DIN;
            #pragma unroll
            for (int kt = 0; kt < 4; ++kt) {
                int k0 = kt * 16 + hi * 8;
                xa[kt][0] = *(const f32x4*)(xr + k0);
                xa[kt][1] = (k0 + 4 < DIN) ? *(const f32x4*)(xr + k0 + 4) : (f32x4){0.f,0.f,0.f,0.f};
            }
        }

        // ---- GEMM1 (A=centres rows, B=x) + phi, two 128-h halves (64 AGPR each) ----
        unsigned pw[32][2];    // lane holds phi[row l31][h = 8b + 4hi + {0..3}] in pw[b]
        #pragma unroll
        for (int h2 = 0; h2 < 2; ++h2) {
            f32x16 a1[4];
            #pragma unroll
            for (int nt = 0; nt < 4; ++nt) a1[nt] = (f32x16){};
            __builtin_amdgcn_s_setprio(1);
            #pragma unroll
            for (int nt = 0; nt < 4; ++nt) {
                int row = (h2 * 4 + nt) * 32 + l31;
                #pragma unroll
                for (int kt = 0; kt < 4; ++kt) {
                    short8 cf = cbf[row * 8 + ((kt * 2 + hi) ^ (row & 7))];
                    a1[nt] = __builtin_amdgcn_mfma_f32_32x32x16_bf16(cf, xb[kt], a1[nt], 0, 0, 0);
                }
            }
            __builtin_amdgcn_s_setprio(0);
            #pragma unroll
            for (int nt = 0; nt < 4; ++nt) {
                int ntg = h2 * 4 + nt;
                float ph[16];
                #pragma unroll
                for (int r = 0; r < 16; ++r) {
                    int h = ntg * 32 + (r & 3) + 8 * (r >> 2) + 4 * hi;
                    f32x2 cn = cnsl[h];
                    float t = fmaf(-2.f, a1[nt][r], x2v);
                    ph[r] = exp2f(fminf(fmaf(cn[0], t, cn[1]), 0.f));
                }
                #pragma unroll
                for (int q = 0; q < 4; ++q) {
                    pw[ntg * 4 + q][0] = pk_bf16(ph[4 * q + 0], ph[4 * q + 1]);
                    pw[ntg * 4 + q][1] = pk_bf16(ph[4 * q + 2], ph[4 * q + 3]);
                }
            }
        }

        // ---- convert next x now (xa dies; only xb/x2 carried through GEMM2) ----
        float x2n = 0.f;
        if (it < 3) {
            float q2 = 0.f;
            #pragma unroll
            for (int kt = 0; kt < 4; ++kt)
                #pragma unroll
                for (int h = 0; h < 2; ++h)
                    #pragma unroll
                    for (int i = 0; i < 4; ++i) q2 = fmaf(xa[kt][h][i], xa[kt][h][i], q2);
            x2n = q2 + __shfl_xor(q2, 32);
            #pragma unroll
            for (int kt = 0; kt < 4; ++kt) {
                union { u32x4 u; short8 s; } a;
                a.u[0] = pk_bf16(xa[kt][0][0], xa[kt][0][1]);
                a.u[1] = pk_bf16(xa[kt][0][2], xa[kt][0][3]);
                a.u[2] = pk_bf16(xa[kt][1][0], xa[kt][1][1]);
                a.u[3] = pk_bf16(xa[kt][1][2], xa[kt][1][3]);
                xb[kt] = a.s;
            }
        }

        // ---- GEMM2: A=W2 (LDS, conflict-free 32-XOR), B=phi (shuffle). 6 N x 16 K ----
        f32x16 a2[6];
        #pragma unroll
        for (int nt = 0; nt < 6; ++nt) a2[nt] = (f32x16){};
        #pragma unroll
        for (int kt = 0; kt < 16; ++kt) {
            const int b = kt * 2;
            int A0 = __shfl((int)pw[b][0],     l31);
            int A1 = __shfl((int)pw[b][1],     l31);
            int C0 = __shfl((int)pw[b + 1][0], l31);
            int C1 = __shfl((int)pw[b + 1][1], l31);
            int B0 = __shfl((int)pw[b][0],     l31 + 32);
            int B1 = __shfl((int)pw[b][1],     l31 + 32);
            int D0 = __shfl((int)pw[b + 1][0], l31 + 32);
            int D1 = __shfl((int)pw[b + 1][1], l31 + 32);
            union { u32x4 u; short8 s; } bf;
            bf.u[0] = (unsigned)(hi ? C0 : A0);
            bf.u[1] = (unsigned)(hi ? C1 : A1);
            bf.u[2] = (unsigned)(hi ? D0 : B0);
            bf.u[3] = (unsigned)(hi ? D1 : B1);

            __builtin_amdgcn_s_setprio(1);
            #pragma unroll
            for (int nt = 0; nt < 6; ++nt) {
                int lrow = nt * 32 + l31;
                short8 wf = w2h[lrow * 32 + ((kt * 2 + hi) ^ l31)];
                a2[nt] = __builtin_amdgcn_mfma_f32_32x32x16_bf16(wf, bf.s, a2[nt], 0, 0, 0);
            }
            __builtin_amdgcn_s_setprio(0);
        }

        // ---- store: lane owns row rbase+l31; f32x4 chunks of 4 consecutive cols ----
        {
            float* op = out + (size_t)(rbase + l31) * DOUT;
            #pragma unroll
            for (int nt = 0; nt < 6; ++nt) {
                #pragma unroll
                for (int q = 0; q < 4; ++q) {
                    int col = f * 192 + nt * 32 + q * 8 + hi * 4;
                    if (col < DOUT) {
                        f32x4 v;
                        v[0] = a2[nt][4 * q + 0]; v[1] = a2[nt][4 * q + 1];
                        v[2] = a2[nt][4 * q + 2]; v[3] = a2[nt][4 * q + 3];
                        *(f32x4*)(op + col) = v;
                    }
                }
            }
        }

        x2v = x2n;
        rbase += 256;   // next task (+8 row-tiles of 32)
    }
}

extern "C" void kernel_launch(void* const* d_in, const int* in_sizes, int n_in,
                              void* d_out, int out_size, void* d_ws, size_t ws_size,
                              hipStream_t stream) {
    const float* x       = (const float*)d_in[0];
    const float* centres = (const float*)d_in[1];
    const float* sigmas  = (const float*)d_in[2];
    const float* W2      = (const float*)d_in[3];
    float* out = (float*)d_out;
    short* ws  = (short*)d_ws;                  // needs 231424 B
    prep<<<dim3(57), dim3(256), 0, stream>>>(centres, sigmas, W2, ws);
    rbf_main<<<dim3(256), dim3(THREADS), 0, stream>>>(x, ws, out);
}